// Round 2
// baseline (7077.142 us; speedup 1.0000x reference)
//
#include <hip/hip_runtime.h>

using short8 = __attribute__((ext_vector_type(8))) short;
using f32x4  = __attribute__((ext_vector_type(4))) float;

typedef unsigned short u16;
typedef unsigned int   u32;

#define T_SEQ 256
#define BATCH 64
#define INP   256
#define HID   1024
#define GDIM  4096
#define KC    1280   // HID + INP
#define OUTD  1024

#define NSL   40     // K slices of 32
#define NSLR  16     // slices with B in registers
#define NSLL  (NSL - NSLR)   // slices with B in LDS (24 -> 48KB)
#define NBLK  256

__device__ __forceinline__ u16 f2bf(float f){
  union { float f; u32 u; } v; v.f = f;
  u32 r = v.u + 0x7fffu + ((v.u >> 16) & 1u);
  return (u16)(r >> 16);
}
__device__ __forceinline__ float sigm(float x){ return 1.f/(1.f+__expf(-x)); }
__device__ __forceinline__ float tanhf_(float x){ return 1.f - 2.f/(__expf(2.f*x)+1.f); }

// ---------------------------------------------------------------------------
// Prep: combined recurrent weights, bf16, gate-interleaved, transposed.
// Wc[n][k], n = 4*j + gate, k<1024 -> Wh[k][gate*1024+j], else Wx[k-1024][...]
// ---------------------------------------------------------------------------
__global__ void build_wc(const float* __restrict__ WhF, const float* __restrict__ WxF,
                         const float* __restrict__ WhB, const float* __restrict__ WxB,
                         u16* __restrict__ WcF, u16* __restrict__ WcB)
{
  const int z = blockIdx.z; const int dir = z >> 2, gate = z & 3;
  const float* Wh = dir ? WhB : WhF;
  const float* Wx = dir ? WxB : WxF;
  u16* Wc = dir ? WcB : WcF;
  const int k0 = blockIdx.x * 64, j0 = blockIdx.y * 64;
  __shared__ float tile[64][65];
  const int t = threadIdx.x;
  #pragma unroll
  for (int i = 0; i < 16; ++i) {
    int idx = i*256 + t; int kr = idx >> 6, jc = idx & 63;
    int k = k0 + kr;
    float v = (k < HID) ? Wh[(size_t)k*GDIM + gate*HID + j0 + jc]
                        : Wx[(size_t)(k-HID)*GDIM + gate*HID + j0 + jc];
    tile[kr][jc] = v;
  }
  __syncthreads();
  #pragma unroll
  for (int i = 0; i < 16; ++i) {
    int idx = i*256 + t; int jc = idx >> 6, kr = idx & 63;
    int n = 4*(j0 + jc) + gate;
    Wc[(size_t)n*KC + k0 + kr] = f2bf(tile[kr][jc]);
  }
}

// W_fc [2048][1024] f32 -> WfcT [1024][2048] bf16 (transposed)
__global__ void build_wfc(const float* __restrict__ Wfc, u16* __restrict__ WfcT)
{
  const int k0 = blockIdx.x * 64;
  const int n0 = blockIdx.y * 64;
  __shared__ float tile[64][65];
  const int t = threadIdx.x;
  #pragma unroll
  for (int i = 0; i < 16; ++i) {
    int idx = i*256 + t; int kr = idx >> 6, nc = idx & 63;
    tile[kr][nc] = Wfc[(size_t)(k0+kr)*OUTD + n0 + nc];
  }
  __syncthreads();
  #pragma unroll
  for (int i = 0; i < 16; ++i) {
    int idx = i*256 + t; int nc = idx >> 6, kr = idx & 63;
    WfcT[(size_t)(n0+nc)*2048 + k0 + kr] = f2bf(tile[kr][nc]);
  }
}

__global__ void conv_x(const float* __restrict__ x, u16* __restrict__ xb, int n)
{
  int i = (blockIdx.x * blockDim.x + threadIdx.x) * 4;
  if (i < n) {
    float4 v = *(const float4*)(x + i);
    u32 lo = (u32)f2bf(v.x) | ((u32)f2bf(v.y) << 16);
    u32 hi = (u32)f2bf(v.z) | ((u32)f2bf(v.w) << 16);
    *(uint2*)(xb + i) = make_uint2(lo, hi);
  }
}

// ---------------------------------------------------------------------------
// Persistent bidirectional LSTM. 256 blocks: blocks [0,128) forward,
// [128,256) backward; each owns 32 gate-cols (8 h-cols) for all 256 steps.
// Weights resident (16 K-slices in VGPRs + 24 in LDS). c in registers.
// Grid barrier between steps (all blocks resident: 48KB LDS, ~190 VGPR).
// ---------------------------------------------------------------------------
__global__ __launch_bounds__(256) void lstm_persist(
    const u16* __restrict__ WcF, const u16* __restrict__ WcB,
    const u16* __restrict__ xb,
    u16* __restrict__ hF, u16* __restrict__ hB,
    const float* __restrict__ bF, const float* __restrict__ bB,
    u16* __restrict__ hs, float* __restrict__ out_tail, int* barcnt)
{
  const int bid = blockIdx.x;
  const int dir = bid >> 7;
  const int nb  = bid & 127;
  const int n0  = nb * 32;                 // gate-col base
  const u16* __restrict__ Wc   = dir ? WcB : WcF;
  const float* __restrict__ bias = dir ? bB : bF;
  u16* __restrict__ hbuf = dir ? hB : hF;

  const int tid  = threadIdx.x;
  const int w    = tid >> 6, lane = tid & 63;
  const int r    = lane & 15, q = lane >> 4;

  __shared__ __align__(16) u16 Bs[NSLL * 2 * 64 * 8];  // 48KB, fragment layout

  // stage LDS half of B: [ks-NSLR][nt][lane][8]
  for (int c = tid; c < NSLL * 128; c += 256) {
    int ks  = NSLR + (c >> 7);
    int rem = c & 127;
    int nt  = rem >> 6, l2 = rem & 63;
    int rr  = l2 & 15,  qq = l2 >> 4;
    *(short8*)&Bs[(size_t)c * 8] =
        *(const short8*)(Wc + (size_t)(n0 + nt*16 + rr) * KC + ks*32 + qq*8);
  }

  // register half of B (static-indexed, fully unrolled)
  short8 breg[NSLR][2];
  #pragma unroll
  for (int ks = 0; ks < NSLR; ++ks)
    #pragma unroll
    for (int nt = 0; nt < 2; ++nt)
      breg[ks][nt] = *(const short8*)(Wc + (size_t)(n0 + nt*16 + r) * KC + ks*32 + q*8);

  // bias for this lane's (writer) columns: j = jbase + nt*4 + (r>>2)
  const int jbase = nb * 8;
  float bia[2][4];
  #pragma unroll
  for (int nt = 0; nt < 2; ++nt)
    #pragma unroll
    for (int g = 0; g < 4; ++g)
      bia[nt][g] = bias[g * HID + jbase + nt*4 + (r >> 2)];

  float creg[2][4];
  #pragma unroll
  for (int nt = 0; nt < 2; ++nt)
    #pragma unroll
    for (int rg = 0; rg < 4; ++rg) creg[nt][rg] = 0.f;

  const int row_a = w * 16 + r;   // A row this lane loads
  __syncthreads();

  for (int s = 0; s < T_SEQ; ++s) {
    const int tt = dir ? (T_SEQ - 1 - s) : s;
    const u16* __restrict__ hprev = hbuf + (s & 1) * (BATCH * HID);
    u16* __restrict__ hnext = hbuf + ((s + 1) & 1) * (BATCH * HID);
    const u16* __restrict__ arow = hprev + (size_t)row_a * HID;
    const u16* __restrict__ axr  = xb + (size_t)tt * BATCH * INP + (size_t)row_a * INP;

    f32x4 acc[2];
    acc[0] = (f32x4)(0.f); acc[1] = (f32x4)(0.f);

    // K-loop: no barriers. A from global (L2-resident), B from regs/LDS.
    #pragma unroll
    for (int ks = 0; ks < NSLR; ++ks) {
      short8 a = *(const short8*)(arow + ks*32 + q*8);
      acc[0] = __builtin_amdgcn_mfma_f32_16x16x32_bf16(a, breg[ks][0], acc[0], 0, 0, 0);
      acc[1] = __builtin_amdgcn_mfma_f32_16x16x32_bf16(a, breg[ks][1], acc[1], 0, 0, 0);
    }
    #pragma unroll
    for (int ks = NSLR; ks < NSL; ++ks) {
      const u16* src = (ks < 32) ? (arow + ks*32 + q*8)
                                 : (axr + (ks - 32)*32 + q*8);
      short8 a  = *(const short8*)src;
      short8 b0 = *(const short8*)&Bs[(((ks - NSLR)*2 + 0)*64 + lane)*8];
      short8 b1 = *(const short8*)&Bs[(((ks - NSLR)*2 + 1)*64 + lane)*8];
      acc[0] = __builtin_amdgcn_mfma_f32_16x16x32_bf16(a, b0, acc[0], 0, 0, 0);
      acc[1] = __builtin_amdgcn_mfma_f32_16x16x32_bf16(a, b1, acc[1], 0, 0, 0);
    }

    // gate combine across interleaved lanes + cell update.
    // acc[nt][reg] = g[row = w*16 + q*4+reg][n = n0 + nt*16 + r], gate = r&3.
    #pragma unroll
    for (int nt = 0; nt < 2; ++nt) {
      #pragma unroll
      for (int rg = 0; rg < 4; ++rg) {
        float v  = acc[nt][rg];
        float x1 = __shfl_xor(v, 1);
        float x2 = __shfl_xor(v, 2);
        float x3 = __shfl_xor(x1, 2);
        if ((r & 3) == 0) {   // writer lane: owns (row, j)
          float gi = v  + bia[nt][0];
          float gf = x1 + bia[nt][1];
          float go = x2 + bia[nt][2];
          float gc = x3 + bia[nt][3];
          float cn = sigm(gf) * creg[nt][rg] + sigm(gi) * tanhf_(gc);
          float hn = sigm(go) * tanhf_(cn);
          creg[nt][rg] = cn;
          int row = w * 16 + q * 4 + rg;
          int j   = jbase + nt * 4 + (r >> 2);
          u16 hb  = f2bf(hn);
          hnext[(size_t)row * HID + j] = hb;
          hs[((size_t)tt * BATCH + row) * 2048 + dir * HID + j] = hb;
          if (s == T_SEQ - 1) {
            out_tail[dir * (BATCH * HID) + (size_t)row * HID + j] = hn;
            out_tail[2 * (BATCH * HID) + dir * (BATCH * HID) + (size_t)row * HID + j] = cn;
          }
        }
      }
    }

    // grid barrier (device-scope): h_next visible to all blocks before next step
    __syncthreads();
    if (tid == 0) {
      __threadfence();
      __hip_atomic_fetch_add(barcnt, 1, __ATOMIC_RELEASE, __HIP_MEMORY_SCOPE_AGENT);
      const int target = NBLK * (s + 1);
      while (__hip_atomic_load(barcnt, __ATOMIC_ACQUIRE, __HIP_MEMORY_SCOPE_AGENT) < target)
        __builtin_amdgcn_s_sleep(1);
      __threadfence();
    }
    __syncthreads();
  }
}

// ---------------------------------------------------------------------------
// Final FC: out[16384][1024] = hs[16384][2048] @ WfcT^T + b_fc, f32 out.
// ---------------------------------------------------------------------------
__global__ __launch_bounds__(256) void fc_kernel(
    const u16* __restrict__ hs, const u16* __restrict__ WfcT,
    const float* __restrict__ bfc, float* __restrict__ out)
{
  const int m0 = blockIdx.x * 128, n0 = blockIdx.y * 128;
  __shared__ __align__(16) u16 As[128 * 32];
  __shared__ __align__(16) u16 Bs[128 * 32];
  const int tid = threadIdx.x;
  const int w = tid >> 6, lane = tid & 63;
  const int r = lane & 15, q = lane >> 4;
  const int wy = w >> 1, wx = w & 1;

  f32x4 acc[4][4];
  #pragma unroll
  for (int a = 0; a < 4; ++a)
    #pragma unroll
    for (int b = 0; b < 4; ++b) acc[a][b] = (f32x4)(0.f);

  const int lr = tid >> 1, lk = (tid & 1) * 16;

  for (int k0 = 0; k0 < 2048; k0 += 32) {
    __syncthreads();
    *(short8*)&As[lr * 32 + lk]     = *(const short8*)(hs   + (size_t)(m0 + lr) * 2048 + k0 + lk);
    *(short8*)&As[lr * 32 + lk + 8] = *(const short8*)(hs   + (size_t)(m0 + lr) * 2048 + k0 + lk + 8);
    *(short8*)&Bs[lr * 32 + lk]     = *(const short8*)(WfcT + (size_t)(n0 + lr) * 2048 + k0 + lk);
    *(short8*)&Bs[lr * 32 + lk + 8] = *(const short8*)(WfcT + (size_t)(n0 + lr) * 2048 + k0 + lk + 8);
    __syncthreads();

    short8 af[4], bf[4];
    #pragma unroll
    for (int mt = 0; mt < 4; ++mt)
      af[mt] = *(const short8*)&As[(wy * 64 + mt * 16 + r) * 32 + q * 8];
    #pragma unroll
    for (int nt = 0; nt < 4; ++nt)
      bf[nt] = *(const short8*)&Bs[(wx * 64 + nt * 16 + r) * 32 + q * 8];
    #pragma unroll
    for (int mt = 0; mt < 4; ++mt)
      #pragma unroll
      for (int nt = 0; nt < 4; ++nt)
        acc[mt][nt] = __builtin_amdgcn_mfma_f32_16x16x32_bf16(af[mt], bf[nt], acc[mt][nt], 0, 0, 0);
  }

  #pragma unroll
  for (int mt = 0; mt < 4; ++mt)
    #pragma unroll
    for (int nt = 0; nt < 4; ++nt)
      #pragma unroll
      for (int reg = 0; reg < 4; ++reg) {
        int m = m0 + wy * 64 + mt * 16 + q * 4 + reg;
        int n = n0 + wx * 64 + nt * 16 + r;
        out[(size_t)m * OUTD + n] = acc[mt][nt][reg] + bfc[n];
      }
}

// ---------------------------------------------------------------------------
extern "C" void kernel_launch(void* const* d_in, const int* in_sizes, int n_in,
                              void* d_out, int out_size, void* d_ws, size_t ws_size,
                              hipStream_t stream)
{
  const float* x   = (const float*)d_in[0];
  const float* WxF = (const float*)d_in[1];
  const float* WhF = (const float*)d_in[2];
  const float* bF  = (const float*)d_in[3];
  const float* WxB = (const float*)d_in[4];
  const float* WhB = (const float*)d_in[5];
  const float* bB  = (const float*)d_in[6];
  const float* Wfc = (const float*)d_in[7];
  const float* bfc = (const float*)d_in[8];
  float* out = (float*)d_out;

  char* ws = (char*)d_ws;
  u16*  WcF   = (u16*)(ws + 0);          // 10485760
  u16*  WcB   = (u16*)(ws + 10485760);   // 10485760
  u16*  WfcT  = (u16*)(ws + 20971520);   // 4194304
  u16*  xb    = (u16*)(ws + 25165824);   // 8388608
  u16*  hF    = (u16*)(ws + 33554432);   // 262144 (2 parities)
  u16*  hB    = (u16*)(ws + 33816576);   // 262144
  u16*  hs    = (u16*)(ws + 34603008);   // 67108864
  int*  barcnt= (int*)(ws + 101711872);  // 256B
  // total ws use: ~102 MB

  hipMemsetAsync(ws + 33554432, 0, 1048576, stream);   // h double-buffers (+ old c slots)
  hipMemsetAsync(barcnt, 0, 256, stream);              // grid-barrier counter

  build_wc <<<dim3(KC/64, HID/64, 8), 256, 0, stream>>>(WhF, WxF, WhB, WxB, WcF, WcB);
  build_wfc<<<dim3(2048/64, OUTD/64), 256, 0, stream>>>(Wfc, WfcT);
  conv_x   <<<(T_SEQ*BATCH*INP)/4/256, 256, 0, stream>>>(x, xb, T_SEQ*BATCH*INP);

  lstm_persist<<<NBLK, 256, 0, stream>>>(WcF, WcB, xb, hF, hB, bF, bB,
                                         hs, out + 16777216, barcnt);

  fc_kernel<<<dim3(16384/128, OUTD/128), 256, 0, stream>>>(hs, WfcT, bfc, out);
}

// Round 3
// 4669.476 us; speedup vs baseline: 1.5156x; 1.5156x over previous
//
#include <hip/hip_runtime.h>

using short8 = __attribute__((ext_vector_type(8))) short;
using f32x4  = __attribute__((ext_vector_type(4))) float;

typedef unsigned short u16;
typedef unsigned int   u32;

#define T_SEQ 256
#define BATCH 64
#define INP   256
#define HID   1024
#define GDIM  4096
#define KC    1280   // HID + INP
#define OUTD  1024

#define NSL   40     // K slices of 32
#define NSLR  16     // slices with B in registers (128 VGPRs)
#define NSLL  (NSL - NSLR)   // 24 slices in LDS -> 48KB
#define NBLK  256
#define DBLK  128    // blocks per direction

__device__ __forceinline__ u16 f2bf(float f){
  union { float f; u32 u; } v; v.f = f;
  u32 r = v.u + 0x7fffu + ((v.u >> 16) & 1u);
  return (u16)(r >> 16);
}
__device__ __forceinline__ float sigm(float x){ return 1.f/(1.f+__expf(-x)); }
__device__ __forceinline__ float tanhf_(float x){ return 1.f - 2.f/(__expf(2.f*x)+1.f); }

// write-through (system-coherent) stores: no dirty L2 lines anywhere
__device__ __forceinline__ void st_u16_wt(u16* p, u16 v){
  asm volatile("global_store_short %0, %1, off sc0 sc1" :: "v"(p), "v"((u32)v) : "memory");
}
__device__ __forceinline__ void st_f32_wt(float* p, float v){
  asm volatile("global_store_dword %0, %1, off sc0 sc1" :: "v"(p), "v"(v) : "memory");
}
__device__ __forceinline__ void st_u32_wt(int* p, u32 v){
  asm volatile("global_store_dword %0, %1, off sc0 sc1" :: "v"(p), "v"(v) : "memory");
}

// ---------------------------------------------------------------------------
// Prep: combined recurrent weights, bf16, gate-interleaved, transposed.
// ---------------------------------------------------------------------------
__global__ void build_wc(const float* __restrict__ WhF, const float* __restrict__ WxF,
                         const float* __restrict__ WhB, const float* __restrict__ WxB,
                         u16* __restrict__ WcF, u16* __restrict__ WcB)
{
  const int z = blockIdx.z; const int dir = z >> 2, gate = z & 3;
  const float* Wh = dir ? WhB : WhF;
  const float* Wx = dir ? WxB : WxF;
  u16* Wc = dir ? WcB : WcF;
  const int k0 = blockIdx.x * 64, j0 = blockIdx.y * 64;
  __shared__ float tile[64][65];
  const int t = threadIdx.x;
  #pragma unroll
  for (int i = 0; i < 16; ++i) {
    int idx = i*256 + t; int kr = idx >> 6, jc = idx & 63;
    int k = k0 + kr;
    float v = (k < HID) ? Wh[(size_t)k*GDIM + gate*HID + j0 + jc]
                        : Wx[(size_t)(k-HID)*GDIM + gate*HID + j0 + jc];
    tile[kr][jc] = v;
  }
  __syncthreads();
  #pragma unroll
  for (int i = 0; i < 16; ++i) {
    int idx = i*256 + t; int jc = idx >> 6, kr = idx & 63;
    int n = 4*(j0 + jc) + gate;
    Wc[(size_t)n*KC + k0 + kr] = f2bf(tile[kr][jc]);
  }
}

__global__ void build_wfc(const float* __restrict__ Wfc, u16* __restrict__ WfcT)
{
  const int k0 = blockIdx.x * 64;
  const int n0 = blockIdx.y * 64;
  __shared__ float tile[64][65];
  const int t = threadIdx.x;
  #pragma unroll
  for (int i = 0; i < 16; ++i) {
    int idx = i*256 + t; int kr = idx >> 6, nc = idx & 63;
    tile[kr][nc] = Wfc[(size_t)(k0+kr)*OUTD + n0 + nc];
  }
  __syncthreads();
  #pragma unroll
  for (int i = 0; i < 16; ++i) {
    int idx = i*256 + t; int nc = idx >> 6, kr = idx & 63;
    WfcT[(size_t)(n0+nc)*2048 + k0 + kr] = f2bf(tile[kr][nc]);
  }
}

__global__ void conv_x(const float* __restrict__ x, u16* __restrict__ xb, int n)
{
  int i = (blockIdx.x * blockDim.x + threadIdx.x) * 4;
  if (i < n) {
    float4 v = *(const float4*)(x + i);
    u32 lo = (u32)f2bf(v.x) | ((u32)f2bf(v.y) << 16);
    u32 hi = (u32)f2bf(v.z) | ((u32)f2bf(v.w) << 16);
    *(uint2*)(xb + i) = make_uint2(lo, hi);
  }
}

// ---------------------------------------------------------------------------
// Persistent bidirectional LSTM. 256 blocks, weights resident in VGPR+LDS.
// Per-step sync: write-through h stores + per-direction flag-array barrier
// (no RMW contention, no L2 writeback; acquire fence = invalidate only).
// ---------------------------------------------------------------------------
__global__ __launch_bounds__(256, 1) void lstm_persist(
    const u16* __restrict__ WcF, const u16* __restrict__ WcB,
    const u16* __restrict__ xb,
    u16* __restrict__ hF, u16* __restrict__ hB,
    const float* __restrict__ bF, const float* __restrict__ bB,
    u16* __restrict__ hs, float* __restrict__ out_tail, int* flags)
{
  const int bid = blockIdx.x;
  const int dir = bid >> 7;
  const int nb  = bid & 127;
  const int n0  = nb * 32;                 // gate-col base
  const u16* __restrict__ Wc   = dir ? WcB : WcF;
  const float* __restrict__ bias = dir ? bB : bF;
  u16* __restrict__ hbuf = dir ? hB : hF;
  int* __restrict__ fl = flags + dir * DBLK;

  const int tid  = threadIdx.x;
  const int w    = tid >> 6, lane = tid & 63;
  const int r    = lane & 15, q = lane >> 4;

  __shared__ __align__(16) u16 Bs[NSLL * 2 * 64 * 8];  // 48KB fragment layout

  for (int c = tid; c < NSLL * 128; c += 256) {
    int ks  = NSLR + (c >> 7);
    int rem = c & 127;
    int nt  = rem >> 6, l2 = rem & 63;
    int rr  = l2 & 15,  qq = l2 >> 4;
    *(short8*)&Bs[(size_t)c * 8] =
        *(const short8*)(Wc + (size_t)(n0 + nt*16 + rr) * KC + ks*32 + qq*8);
  }

  short8 breg[NSLR][2];
  #pragma unroll
  for (int ks = 0; ks < NSLR; ++ks)
    #pragma unroll
    for (int nt = 0; nt < 2; ++nt)
      breg[ks][nt] = *(const short8*)(Wc + (size_t)(n0 + nt*16 + r) * KC + ks*32 + q*8);

  const int jbase = nb * 8;
  float bia[2][4];
  #pragma unroll
  for (int nt = 0; nt < 2; ++nt)
    #pragma unroll
    for (int g = 0; g < 4; ++g)
      bia[nt][g] = bias[g * HID + jbase + nt*4 + (r >> 2)];

  float creg[2][4];
  #pragma unroll
  for (int nt = 0; nt < 2; ++nt)
    #pragma unroll
    for (int rg = 0; rg < 4; ++rg) creg[nt][rg] = 0.f;

  const int row_a = w * 16 + r;
  __syncthreads();

  for (int s = 0; s < T_SEQ; ++s) {
    const int tt = dir ? (T_SEQ - 1 - s) : s;
    const u16* __restrict__ hprev = hbuf + (s & 1) * (BATCH * HID);
    u16* __restrict__ hnext = hbuf + ((s + 1) & 1) * (BATCH * HID);
    const u16* __restrict__ arow = hprev + (size_t)row_a * HID;
    const u16* __restrict__ axr  = xb + (size_t)tt * BATCH * INP + (size_t)row_a * INP;

    f32x4 acc[2];
    acc[0] = (f32x4)(0.f); acc[1] = (f32x4)(0.f);

    #pragma unroll
    for (int ks = 0; ks < NSLR; ++ks) {
      short8 a = *(const short8*)(arow + ks*32 + q*8);
      acc[0] = __builtin_amdgcn_mfma_f32_16x16x32_bf16(a, breg[ks][0], acc[0], 0, 0, 0);
      acc[1] = __builtin_amdgcn_mfma_f32_16x16x32_bf16(a, breg[ks][1], acc[1], 0, 0, 0);
    }
    #pragma unroll
    for (int ks = NSLR; ks < NSL; ++ks) {
      const u16* src = (ks < 32) ? (arow + ks*32 + q*8)
                                 : (axr + (ks - 32)*32 + q*8);
      short8 a  = *(const short8*)src;
      short8 b0 = *(const short8*)&Bs[(((ks - NSLR)*2 + 0)*64 + lane)*8];
      short8 b1 = *(const short8*)&Bs[(((ks - NSLR)*2 + 1)*64 + lane)*8];
      acc[0] = __builtin_amdgcn_mfma_f32_16x16x32_bf16(a, b0, acc[0], 0, 0, 0);
      acc[1] = __builtin_amdgcn_mfma_f32_16x16x32_bf16(a, b1, acc[1], 0, 0, 0);
    }

    // gate combine + cell update; all stores write-through (never dirty L2)
    #pragma unroll
    for (int nt = 0; nt < 2; ++nt) {
      #pragma unroll
      for (int rg = 0; rg < 4; ++rg) {
        float v  = acc[nt][rg];
        float x1 = __shfl_xor(v, 1);
        float x2 = __shfl_xor(v, 2);
        float x3 = __shfl_xor(x1, 2);
        if ((r & 3) == 0) {
          float gi = v  + bia[nt][0];
          float gf = x1 + bia[nt][1];
          float go = x2 + bia[nt][2];
          float gc = x3 + bia[nt][3];
          float cn = sigm(gf) * creg[nt][rg] + sigm(gi) * tanhf_(gc);
          float hn = sigm(go) * tanhf_(cn);
          creg[nt][rg] = cn;
          int row = w * 16 + q * 4 + rg;
          int j   = jbase + nt * 4 + (r >> 2);
          u16 hb  = f2bf(hn);
          st_u16_wt(hnext + (size_t)row * HID + j, hb);
          st_u16_wt(hs + ((size_t)tt * BATCH + row) * 2048 + dir * HID + j, hb);
          if (s == T_SEQ - 1) {
            st_f32_wt(out_tail + dir * (BATCH * HID) + (size_t)row * HID + j, hn);
            st_f32_wt(out_tail + 2 * (BATCH * HID) + dir * (BATCH * HID) + (size_t)row * HID + j, cn);
          }
        }
      }
    }

    if (s < T_SEQ - 1) {
      // release: drain this wave's write-through stores to coherence point
      asm volatile("s_waitcnt vmcnt(0)" ::: "memory");
      __syncthreads();   // all waves' stores drained
      if (tid == 0) st_u32_wt(fl + nb, (u32)(s + 1));
      if (w == 0) {
        const int tgt = s + 1;
        int ok;
        do {
          int f0 = __hip_atomic_load(fl + 2*lane,     __ATOMIC_RELAXED, __HIP_MEMORY_SCOPE_AGENT);
          int f1 = __hip_atomic_load(fl + 2*lane + 1, __ATOMIC_RELAXED, __HIP_MEMORY_SCOPE_AGENT);
          ok = (f0 >= tgt) && (f1 >= tgt);
        } while (!__all(ok));
      }
      __syncthreads();
      // acquire: invalidate stale L1/L2 copies of h (weights live in LDS/VGPR)
      __builtin_amdgcn_fence(__ATOMIC_ACQUIRE, "agent");
    }
  }
}

// ---------------------------------------------------------------------------
// Final FC: out[16384][1024] = hs[16384][2048] @ WfcT^T + b_fc, f32 out.
// ---------------------------------------------------------------------------
__global__ __launch_bounds__(256) void fc_kernel(
    const u16* __restrict__ hs, const u16* __restrict__ WfcT,
    const float* __restrict__ bfc, float* __restrict__ out)
{
  const int m0 = blockIdx.x * 128, n0 = blockIdx.y * 128;
  __shared__ __align__(16) u16 As[128 * 32];
  __shared__ __align__(16) u16 Bs[128 * 32];
  const int tid = threadIdx.x;
  const int w = tid >> 6, lane = tid & 63;
  const int r = lane & 15, q = lane >> 4;
  const int wy = w >> 1, wx = w & 1;

  f32x4 acc[4][4];
  #pragma unroll
  for (int a = 0; a < 4; ++a)
    #pragma unroll
    for (int b = 0; b < 4; ++b) acc[a][b] = (f32x4)(0.f);

  const int lr = tid >> 1, lk = (tid & 1) * 16;

  for (int k0 = 0; k0 < 2048; k0 += 32) {
    __syncthreads();
    *(short8*)&As[lr * 32 + lk]     = *(const short8*)(hs   + (size_t)(m0 + lr) * 2048 + k0 + lk);
    *(short8*)&As[lr * 32 + lk + 8] = *(const short8*)(hs   + (size_t)(m0 + lr) * 2048 + k0 + lk + 8);
    *(short8*)&Bs[lr * 32 + lk]     = *(const short8*)(WfcT + (size_t)(n0 + lr) * 2048 + k0 + lk);
    *(short8*)&Bs[lr * 32 + lk + 8] = *(const short8*)(WfcT + (size_t)(n0 + lr) * 2048 + k0 + lk + 8);
    __syncthreads();

    short8 af[4], bf[4];
    #pragma unroll
    for (int mt = 0; mt < 4; ++mt)
      af[mt] = *(const short8*)&As[(wy * 64 + mt * 16 + r) * 32 + q * 8];
    #pragma unroll
    for (int nt = 0; nt < 4; ++nt)
      bf[nt] = *(const short8*)&Bs[(wx * 64 + nt * 16 + r) * 32 + q * 8];
    #pragma unroll
    for (int mt = 0; mt < 4; ++mt)
      #pragma unroll
      for (int nt = 0; nt < 4; ++nt)
        acc[mt][nt] = __builtin_amdgcn_mfma_f32_16x16x32_bf16(af[mt], bf[nt], acc[mt][nt], 0, 0, 0);
  }

  #pragma unroll
  for (int mt = 0; mt < 4; ++mt)
    #pragma unroll
    for (int nt = 0; nt < 4; ++nt)
      #pragma unroll
      for (int reg = 0; reg < 4; ++reg) {
        int m = m0 + wy * 64 + mt * 16 + q * 4 + reg;
        int n = n0 + wx * 64 + nt * 16 + r;
        out[(size_t)m * OUTD + n] = acc[mt][nt][reg] + bfc[n];
      }
}

// ---------------------------------------------------------------------------
extern "C" void kernel_launch(void* const* d_in, const int* in_sizes, int n_in,
                              void* d_out, int out_size, void* d_ws, size_t ws_size,
                              hipStream_t stream)
{
  const float* x   = (const float*)d_in[0];
  const float* WxF = (const float*)d_in[1];
  const float* WhF = (const float*)d_in[2];
  const float* bF  = (const float*)d_in[3];
  const float* WxB = (const float*)d_in[4];
  const float* WhB = (const float*)d_in[5];
  const float* bB  = (const float*)d_in[6];
  const float* Wfc = (const float*)d_in[7];
  const float* bfc = (const float*)d_in[8];
  float* out = (float*)d_out;

  char* ws = (char*)d_ws;
  u16*  WcF   = (u16*)(ws + 0);          // 10485760
  u16*  WcB   = (u16*)(ws + 10485760);   // 10485760
  u16*  WfcT  = (u16*)(ws + 20971520);   // 4194304
  u16*  xb    = (u16*)(ws + 25165824);   // 8388608
  u16*  hF    = (u16*)(ws + 33554432);   // 262144 (2 parities)
  u16*  hB    = (u16*)(ws + 33816576);   // 262144
  u16*  hs    = (u16*)(ws + 34603008);   // 67108864
  int*  flags = (int*)(ws + 101711872);  // 1KB (256 ints)

  hipMemsetAsync(ws + 33554432, 0, 1048576, stream);  // h double-buffers
  hipMemsetAsync(flags, 0, 1024, stream);             // barrier flags

  build_wc <<<dim3(KC/64, HID/64, 8), 256, 0, stream>>>(WhF, WxF, WhB, WxB, WcF, WcB);
  build_wfc<<<dim3(2048/64, OUTD/64), 256, 0, stream>>>(Wfc, WfcT);
  conv_x   <<<(T_SEQ*BATCH*INP)/4/256, 256, 0, stream>>>(x, xb, T_SEQ*BATCH*INP);

  lstm_persist<<<NBLK, 256, 0, stream>>>(WcF, WcB, xb, hF, hB, bF, bB,
                                         hs, out + 16777216, flags);

  fc_kernel<<<dim3(16384/128, OUTD/128), 256, 0, stream>>>(hs, WfcT, bfc, out);
}

// Round 4
// 4146.219 us; speedup vs baseline: 1.7069x; 1.1262x over previous
//
#include <hip/hip_runtime.h>

using short8 = __attribute__((ext_vector_type(8))) short;
using f32x4  = __attribute__((ext_vector_type(4))) float;

typedef unsigned short u16;
typedef unsigned int   u32;

#define T_SEQ 256
#define BATCH 64
#define INP   256
#define HID   1024
#define GDIM  4096
#define KC    1280   // HID + INP
#define OUTD  1024

#define NSL   40     // K slices of 32 (32 h-slices + 8 x-slices)
#define NBLK  256
#define DBLK  128    // blocks per direction
#define LDSB  (NSL * 2 * 64 * 8 * 2)   // 81920 bytes of dynamic LDS

__device__ __forceinline__ u16 f2bf(float f){
  union { float f; u32 u; } v; v.f = f;
  u32 r = v.u + 0x7fffu + ((v.u >> 16) & 1u);
  return (u16)(r >> 16);
}
__device__ __forceinline__ float sigm(float x){ return 1.f/(1.f+__expf(-x)); }
__device__ __forceinline__ float tanhf_(float x){ return 1.f - 2.f/(__expf(2.f*x)+1.f); }

// write-through (coherent) stores: land at IC, never dirty L2
__device__ __forceinline__ void st_u16_wt(u16* p, u16 v){
  asm volatile("global_store_short %0, %1, off sc0 sc1" :: "v"(p), "v"((u32)v) : "memory");
}
__device__ __forceinline__ void st_f32_wt(float* p, float v){
  asm volatile("global_store_dword %0, %1, off sc0 sc1" :: "v"(p), "v"(v) : "memory");
}
__device__ __forceinline__ void st_u32_wt(int* p, u32 v){
  asm volatile("global_store_dword %0, %1, off sc0 sc1" :: "v"(p), "v"(v) : "memory");
}

// ---------------------------------------------------------------------------
// Prep: combined recurrent weights, bf16, gate-interleaved, transposed.
// Wc[n][k], n = 4*j + gate; k<1024 -> Wh[k][gate*1024+j], else Wx[k-1024][...]
// ---------------------------------------------------------------------------
__global__ void build_wc(const float* __restrict__ WhF, const float* __restrict__ WxF,
                         const float* __restrict__ WhB, const float* __restrict__ WxB,
                         u16* __restrict__ WcF, u16* __restrict__ WcB)
{
  const int z = blockIdx.z; const int dir = z >> 2, gate = z & 3;
  const float* Wh = dir ? WhB : WhF;
  const float* Wx = dir ? WxB : WxF;
  u16* Wc = dir ? WcB : WcF;
  const int k0 = blockIdx.x * 64, j0 = blockIdx.y * 64;
  __shared__ float tile[64][65];
  const int t = threadIdx.x;
  #pragma unroll
  for (int i = 0; i < 16; ++i) {
    int idx = i*256 + t; int kr = idx >> 6, jc = idx & 63;
    int k = k0 + kr;
    float v = (k < HID) ? Wh[(size_t)k*GDIM + gate*HID + j0 + jc]
                        : Wx[(size_t)(k-HID)*GDIM + gate*HID + j0 + jc];
    tile[kr][jc] = v;
  }
  __syncthreads();
  #pragma unroll
  for (int i = 0; i < 16; ++i) {
    int idx = i*256 + t; int jc = idx >> 6, kr = idx & 63;
    int n = 4*(j0 + jc) + gate;
    Wc[(size_t)n*KC + k0 + kr] = f2bf(tile[kr][jc]);
  }
}

__global__ void build_wfc(const float* __restrict__ Wfc, u16* __restrict__ WfcT)
{
  const int k0 = blockIdx.x * 64;
  const int n0 = blockIdx.y * 64;
  __shared__ float tile[64][65];
  const int t = threadIdx.x;
  #pragma unroll
  for (int i = 0; i < 16; ++i) {
    int idx = i*256 + t; int kr = idx >> 6, nc = idx & 63;
    tile[kr][nc] = Wfc[(size_t)(k0+kr)*OUTD + n0 + nc];
  }
  __syncthreads();
  #pragma unroll
  for (int i = 0; i < 16; ++i) {
    int idx = i*256 + t; int nc = idx >> 6, kr = idx & 63;
    WfcT[(size_t)(n0+nc)*2048 + k0 + kr] = f2bf(tile[kr][nc]);
  }
}

__global__ void conv_x(const float* __restrict__ x, u16* __restrict__ xb, int n)
{
  int i = (blockIdx.x * blockDim.x + threadIdx.x) * 4;
  if (i < n) {
    float4 v = *(const float4*)(x + i);
    u32 lo = (u32)f2bf(v.x) | ((u32)f2bf(v.y) << 16);
    u32 hi = (u32)f2bf(v.z) | ((u32)f2bf(v.w) << 16);
    *(uint2*)(xb + i) = make_uint2(lo, hi);
  }
}

// ---------------------------------------------------------------------------
// Persistent bidirectional LSTM. 256 blocks (128/dir), each owns 32 gate-cols
// (8 h-cols) for all 256 steps. All B-weights resident in 80KB dynamic LDS
// (fragment layout, no VGPR spill). c in registers. Per-step sync:
// write-through h stores + flag array + acquire(agent) invalidate.
// ---------------------------------------------------------------------------
__global__ __launch_bounds__(256, 1) void lstm_persist(
    const u16* __restrict__ WcF, const u16* __restrict__ WcB,
    const u16* __restrict__ xb,
    u16* __restrict__ hF, u16* __restrict__ hB,
    const float* __restrict__ bF, const float* __restrict__ bB,
    u16* __restrict__ hs, float* __restrict__ out_tail, int* flags)
{
  extern __shared__ __align__(16) u16 Bs[];   // [NSL][2][64][8]

  const int bid = blockIdx.x;
  const int dir = bid >> 7;
  const int nb  = bid & 127;
  const int n0  = nb * 32;                 // gate-col base
  const u16* __restrict__ Wc   = dir ? WcB : WcF;
  const float* __restrict__ bias = dir ? bB : bF;
  u16* __restrict__ hbuf = dir ? hB : hF;
  int* __restrict__ fl = flags + dir * DBLK;

  const int tid  = threadIdx.x;
  const int w    = tid >> 6, lane = tid & 63;
  const int r    = lane & 15, q = lane >> 4;

  // stage ALL B fragments into LDS: chunk c -> [ks][nt][lane] 16B
  for (int c = tid; c < NSL * 128; c += 256) {
    int ks  = c >> 7;
    int rem = c & 127;
    int nt  = rem >> 6, l2 = rem & 63;
    int rr  = l2 & 15,  qq = l2 >> 4;
    *(short8*)&Bs[(size_t)c * 8] =
        *(const short8*)(Wc + (size_t)(n0 + nt*16 + rr) * KC + ks*32 + qq*8);
  }

  const int jbase = nb * 8;
  float bia[2][4];
  #pragma unroll
  for (int nt = 0; nt < 2; ++nt)
    #pragma unroll
    for (int g = 0; g < 4; ++g)
      bia[nt][g] = bias[g * HID + jbase + nt*4 + (r >> 2)];

  float creg[2][4];
  #pragma unroll
  for (int nt = 0; nt < 2; ++nt)
    #pragma unroll
    for (int rg = 0; rg < 4; ++rg) creg[nt][rg] = 0.f;

  const int row_a = w * 16 + r;

  // prefetch x-part A fragments for the first step
  short8 ax[8];
  {
    const int tt0 = dir ? (T_SEQ - 1) : 0;
    const u16* axr = xb + ((size_t)tt0 * BATCH + row_a) * INP;
    #pragma unroll
    for (int kx = 0; kx < 8; ++kx) ax[kx] = *(const short8*)(axr + kx*32 + q*8);
  }
  __syncthreads();   // Bs staging complete

  for (int s = 0; s < T_SEQ; ++s) {
    const int tt = dir ? (T_SEQ - 1 - s) : s;
    const u16* __restrict__ hprev = hbuf + (s & 1) * (BATCH * HID);
    u16* __restrict__ hnext = hbuf + ((s + 1) & 1) * (BATCH * HID);
    const u16* __restrict__ arow = hprev + (size_t)row_a * HID;

    f32x4 acc[2];
    acc[0] = (f32x4)(0.f); acc[1] = (f32x4)(0.f);

    // h part: A from global (cached), B from LDS
    #pragma unroll
    for (int ks = 0; ks < 32; ++ks) {
      short8 a  = *(const short8*)(arow + ks*32 + q*8);
      short8 b0 = *(const short8*)&Bs[((ks*2 + 0)*64 + lane)*8];
      short8 b1 = *(const short8*)&Bs[((ks*2 + 1)*64 + lane)*8];
      acc[0] = __builtin_amdgcn_mfma_f32_16x16x32_bf16(a, b0, acc[0], 0, 0, 0);
      acc[1] = __builtin_amdgcn_mfma_f32_16x16x32_bf16(a, b1, acc[1], 0, 0, 0);
    }
    // x part: A from prefetched registers
    #pragma unroll
    for (int kx = 0; kx < 8; ++kx) {
      int ks = 32 + kx;
      short8 b0 = *(const short8*)&Bs[((ks*2 + 0)*64 + lane)*8];
      short8 b1 = *(const short8*)&Bs[((ks*2 + 1)*64 + lane)*8];
      acc[0] = __builtin_amdgcn_mfma_f32_16x16x32_bf16(ax[kx], b0, acc[0], 0, 0, 0);
      acc[1] = __builtin_amdgcn_mfma_f32_16x16x32_bf16(ax[kx], b1, acc[1], 0, 0, 0);
    }

    // prefetch next step's x fragments (overlaps cell update; drained below)
    if (s < T_SEQ - 1) {
      const int tn = dir ? (T_SEQ - 2 - s) : (s + 1);
      const u16* axr = xb + ((size_t)tn * BATCH + row_a) * INP;
      #pragma unroll
      for (int kx = 0; kx < 8; ++kx) ax[kx] = *(const short8*)(axr + kx*32 + q*8);
    }

    // gate combine + cell update; hnext stores write-through
    u16  hbv[2][4];
    float hnv[2][4];
    #pragma unroll
    for (int nt = 0; nt < 2; ++nt) {
      #pragma unroll
      for (int rg = 0; rg < 4; ++rg) {
        float v  = acc[nt][rg];
        float x1 = __shfl_xor(v, 1);
        float x2 = __shfl_xor(v, 2);
        float x3 = __shfl_xor(x1, 2);
        if ((r & 3) == 0) {
          float gi = v  + bia[nt][0];
          float gf = x1 + bia[nt][1];
          float go = x2 + bia[nt][2];
          float gc = x3 + bia[nt][3];
          float cn = sigm(gf) * creg[nt][rg] + sigm(gi) * tanhf_(gc);
          float hn = sigm(go) * tanhf_(cn);
          creg[nt][rg] = cn;
          hnv[nt][rg] = hn;
          u16 hb = f2bf(hn);
          hbv[nt][rg] = hb;
          int row = w * 16 + q * 4 + rg;
          int j   = jbase + nt * 4 + (r >> 2);
          st_u16_wt(hnext + (size_t)row * HID + j, hb);
        }
      }
    }

    if (s < T_SEQ - 1) {
      // release: drain write-through h stores to the coherence point
      asm volatile("s_waitcnt vmcnt(0)" ::: "memory");
      __syncthreads();
      if (tid == 0) st_u32_wt(fl + nb, (u32)(s + 1));
      // hs stores off the critical path (read only after kernel end)
      #pragma unroll
      for (int nt = 0; nt < 2; ++nt)
        #pragma unroll
        for (int rg = 0; rg < 4; ++rg)
          if ((r & 3) == 0) {
            int row = w * 16 + q * 4 + rg;
            int j   = jbase + nt * 4 + (r >> 2);
            st_u16_wt(hs + ((size_t)tt * BATCH + row) * 2048 + dir * HID + j, hbv[nt][rg]);
          }
      if (w == 0) {
        const int tgt = s + 1;
        int ok;
        do {
          int f0 = __hip_atomic_load(fl + 2*lane,     __ATOMIC_RELAXED, __HIP_MEMORY_SCOPE_AGENT);
          int f1 = __hip_atomic_load(fl + 2*lane + 1, __ATOMIC_RELAXED, __HIP_MEMORY_SCOPE_AGENT);
          ok = (f0 >= tgt) && (f1 >= tgt);
          if (!__all(ok)) __builtin_amdgcn_s_sleep(1);
          else break;
        } while (true);
      }
      __syncthreads();
      // acquire: invalidate stale L1/L2 h copies (weights live in LDS)
      __builtin_amdgcn_fence(__ATOMIC_ACQUIRE, "agent");
    } else {
      // final step: hs + state outputs
      #pragma unroll
      for (int nt = 0; nt < 2; ++nt)
        #pragma unroll
        for (int rg = 0; rg < 4; ++rg)
          if ((r & 3) == 0) {
            int row = w * 16 + q * 4 + rg;
            int j   = jbase + nt * 4 + (r >> 2);
            st_u16_wt(hs + ((size_t)tt * BATCH + row) * 2048 + dir * HID + j, hbv[nt][rg]);
            st_f32_wt(out_tail + dir * (BATCH * HID) + (size_t)row * HID + j, hnv[nt][rg]);
            st_f32_wt(out_tail + 2 * (BATCH * HID) + dir * (BATCH * HID) + (size_t)row * HID + j, creg[nt][rg]);
          }
    }
  }
}

// ---------------------------------------------------------------------------
// Final FC: out[16384][1024] = hs[16384][2048] @ WfcT^T + b_fc, f32 out.
// ---------------------------------------------------------------------------
__global__ __launch_bounds__(256) void fc_kernel(
    const u16* __restrict__ hs, const u16* __restrict__ WfcT,
    const float* __restrict__ bfc, float* __restrict__ out)
{
  const int m0 = blockIdx.x * 128, n0 = blockIdx.y * 128;
  __shared__ __align__(16) u16 As[128 * 32];
  __shared__ __align__(16) u16 Bs[128 * 32];
  const int tid = threadIdx.x;
  const int w = tid >> 6, lane = tid & 63;
  const int r = lane & 15, q = lane >> 4;
  const int wy = w >> 1, wx = w & 1;

  f32x4 acc[4][4];
  #pragma unroll
  for (int a = 0; a < 4; ++a)
    #pragma unroll
    for (int b = 0; b < 4; ++b) acc[a][b] = (f32x4)(0.f);

  const int lr = tid >> 1, lk = (tid & 1) * 16;

  for (int k0 = 0; k0 < 2048; k0 += 32) {
    __syncthreads();
    *(short8*)&As[lr * 32 + lk]     = *(const short8*)(hs   + (size_t)(m0 + lr) * 2048 + k0 + lk);
    *(short8*)&As[lr * 32 + lk + 8] = *(const short8*)(hs   + (size_t)(m0 + lr) * 2048 + k0 + lk + 8);
    *(short8*)&Bs[lr * 32 + lk]     = *(const short8*)(WfcT + (size_t)(n0 + lr) * 2048 + k0 + lk);
    *(short8*)&Bs[lr * 32 + lk + 8] = *(const short8*)(WfcT + (size_t)(n0 + lr) * 2048 + k0 + lk + 8);
    __syncthreads();

    short8 af[4], bf[4];
    #pragma unroll
    for (int mt = 0; mt < 4; ++mt)
      af[mt] = *(const short8*)&As[(wy * 64 + mt * 16 + r) * 32 + q * 8];
    #pragma unroll
    for (int nt = 0; nt < 4; ++nt)
      bf[nt] = *(const short8*)&Bs[(wx * 64 + nt * 16 + r) * 32 + q * 8];
    #pragma unroll
    for (int mt = 0; mt < 4; ++mt)
      #pragma unroll
      for (int nt = 0; nt < 4; ++nt)
        acc[mt][nt] = __builtin_amdgcn_mfma_f32_16x16x32_bf16(af[mt], bf[nt], acc[mt][nt], 0, 0, 0);
  }

  #pragma unroll
  for (int mt = 0; mt < 4; ++mt)
    #pragma unroll
    for (int nt = 0; nt < 4; ++nt)
      #pragma unroll
      for (int reg = 0; reg < 4; ++reg) {
        int m = m0 + wy * 64 + mt * 16 + q * 4 + reg;
        int n = n0 + wx * 64 + nt * 16 + r;
        out[(size_t)m * OUTD + n] = acc[mt][nt][reg] + bfc[n];
      }
}

// ---------------------------------------------------------------------------
extern "C" void kernel_launch(void* const* d_in, const int* in_sizes, int n_in,
                              void* d_out, int out_size, void* d_ws, size_t ws_size,
                              hipStream_t stream)
{
  const float* x   = (const float*)d_in[0];
  const float* WxF = (const float*)d_in[1];
  const float* WhF = (const float*)d_in[2];
  const float* bF  = (const float*)d_in[3];
  const float* WxB = (const float*)d_in[4];
  const float* WhB = (const float*)d_in[5];
  const float* bB  = (const float*)d_in[6];
  const float* Wfc = (const float*)d_in[7];
  const float* bfc = (const float*)d_in[8];
  float* out = (float*)d_out;

  char* ws = (char*)d_ws;
  u16*  WcF   = (u16*)(ws + 0);          // 10485760
  u16*  WcB   = (u16*)(ws + 10485760);   // 10485760
  u16*  WfcT  = (u16*)(ws + 20971520);   // 4194304
  u16*  xb    = (u16*)(ws + 25165824);   // 8388608
  u16*  hF    = (u16*)(ws + 33554432);   // 262144 (2 parities)
  u16*  hB    = (u16*)(ws + 33816576);   // 262144
  u16*  hs    = (u16*)(ws + 34603008);   // 67108864
  int*  flags = (int*)(ws + 101711872);  // 1KB (256 ints)

  hipMemsetAsync(ws + 33554432, 0, 1048576, stream);  // h double-buffers
  hipMemsetAsync(flags, 0, 1024, stream);             // barrier flags

  hipFuncSetAttribute((const void*)lstm_persist,
                      hipFuncAttributeMaxDynamicSharedMemorySize, LDSB);

  build_wc <<<dim3(KC/64, HID/64, 8), 256, 0, stream>>>(WhF, WxF, WhB, WxB, WcF, WcB);
  build_wfc<<<dim3(2048/64, OUTD/64), 256, 0, stream>>>(Wfc, WfcT);
  conv_x   <<<(T_SEQ*BATCH*INP)/4/256, 256, 0, stream>>>(x, xb, T_SEQ*BATCH*INP);

  lstm_persist<<<NBLK, 256, LDSB, stream>>>(WcF, WcB, xb, hF, hB, bF, bB,
                                            hs, out + 16777216, flags);

  fc_kernel<<<dim3(16384/128, OUTD/128), 256, 0, stream>>>(hs, WfcT, bfc, out);
}

// Round 5
// 3064.146 us; speedup vs baseline: 2.3097x; 1.3531x over previous
//
#include <hip/hip_runtime.h>

using short8 = __attribute__((ext_vector_type(8))) short;
using f32x4  = __attribute__((ext_vector_type(4))) float;

typedef unsigned short u16;
typedef unsigned int   u32;

#define T_SEQ 256
#define BATCH 64
#define INP   256
#define HID   1024
#define GDIM  4096
#define KC    1280   // HID + INP
#define OUTD  1024

#define NSL   40     // K slices of 32 (32 h-slices + 8 x-slices)
#define NBLK  256
#define DBLK  128    // blocks per direction
#define LDSB  (NSL * 2 * 64 * 8 * 2)   // 81920 bytes dynamic LDS

__device__ __forceinline__ u16 f2bf(float f){
  union { float f; u32 u; } v; v.f = f;
  u32 r = v.u + 0x7fffu + ((v.u >> 16) & 1u);
  return (u16)(r >> 16);
}
__device__ __forceinline__ float sigm(float x){ return 1.f/(1.f+__expf(-x)); }
__device__ __forceinline__ float tanhf_(float x){ return 1.f - 2.f/(__expf(2.f*x)+1.f); }

// write-through (coherent) stores: visible at IC, never dirty remote L2
__device__ __forceinline__ void st_u32_wt(u32* p, u32 v){
  asm volatile("global_store_dword %0, %1, off sc0 sc1" :: "v"(p), "v"(v) : "memory");
}
__device__ __forceinline__ void st_f32_wt(float* p, float v){
  asm volatile("global_store_dword %0, %1, off sc0 sc1" :: "v"(p), "v"(v) : "memory");
}

// ---------------------------------------------------------------------------
// Prep: combined recurrent weights, bf16, block-permuted column order.
// Block nb owns global gate-cols [nb*32, nb*32+32). Within a block:
//   n = nb*32 + nt*16 + rq*4 + gate, encoding h-col j = nb*8 + 2*rq + nt.
// Rows: k<1024 -> Wh[k][gate*1024+j], k>=1024 -> Wx[k-1024][gate*1024+j].
// ---------------------------------------------------------------------------
__global__ void build_wc(const float* __restrict__ WhF, const float* __restrict__ WxF,
                         const float* __restrict__ WhB, const float* __restrict__ WxB,
                         u16* __restrict__ WcF, u16* __restrict__ WcB)
{
  const int z = blockIdx.z; const int dir = z >> 2, gate = z & 3;
  const float* Wh = dir ? WhB : WhF;
  const float* Wx = dir ? WxB : WxF;
  u16* Wc = dir ? WcB : WcF;
  const int k0 = blockIdx.x * 64, j0 = blockIdx.y * 64;
  __shared__ float tile[64][65];
  const int t = threadIdx.x;
  #pragma unroll
  for (int i = 0; i < 16; ++i) {
    int idx = i*256 + t; int kr = idx >> 6, jc = idx & 63;
    int k = k0 + kr;
    float v = (k < HID) ? Wh[(size_t)k*GDIM + gate*HID + j0 + jc]
                        : Wx[(size_t)(k-HID)*GDIM + gate*HID + j0 + jc];
    tile[kr][jc] = v;
  }
  __syncthreads();
  #pragma unroll
  for (int i = 0; i < 16; ++i) {
    int idx = i*256 + t; int jc = idx >> 6, kr = idx & 63;
    int j  = j0 + jc;
    int nb = j >> 3, jl = j & 7;
    int nt = jl & 1, rq = jl >> 1;
    int n  = nb*32 + nt*16 + rq*4 + gate;
    Wc[(size_t)n*KC + k0 + kr] = f2bf(tile[kr][jc]);
  }
}

__global__ void build_wfc(const float* __restrict__ Wfc, u16* __restrict__ WfcT)
{
  const int k0 = blockIdx.x * 64;
  const int n0 = blockIdx.y * 64;
  __shared__ float tile[64][65];
  const int t = threadIdx.x;
  #pragma unroll
  for (int i = 0; i < 16; ++i) {
    int idx = i*256 + t; int kr = idx >> 6, nc = idx & 63;
    tile[kr][nc] = Wfc[(size_t)(k0+kr)*OUTD + n0 + nc];
  }
  __syncthreads();
  #pragma unroll
  for (int i = 0; i < 16; ++i) {
    int idx = i*256 + t; int nc = idx >> 6, kr = idx & 63;
    WfcT[(size_t)(n0+nc)*2048 + k0 + kr] = f2bf(tile[kr][nc]);
  }
}

__global__ void conv_x(const float* __restrict__ x, u16* __restrict__ xb, int n)
{
  int i = (blockIdx.x * blockDim.x + threadIdx.x) * 4;
  if (i < n) {
    float4 v = *(const float4*)(x + i);
    u32 lo = (u32)f2bf(v.x) | ((u32)f2bf(v.y) << 16);
    u32 hi = (u32)f2bf(v.z) | ((u32)f2bf(v.w) << 16);
    *(uint2*)(xb + i) = make_uint2(lo, hi);
  }
}

// ---------------------------------------------------------------------------
// Persistent bidirectional LSTM. 256 blocks (128/dir), each owns 8 h-cols.
// Weights resident in 80KB LDS. c in registers. h history lives in hs
// (write-once addresses): producers store write-through + flag; consumers
// do flag-gated NORMAL cached loads -> no per-step fence, L2 stays warm
// and shares the h broadcast among co-resident blocks on each XCD.
// ---------------------------------------------------------------------------
__global__ __launch_bounds__(256, 1) void lstm_persist(
    const u16* __restrict__ WcF, const u16* __restrict__ WcB,
    const u16* __restrict__ xb,
    const float* __restrict__ bF, const float* __restrict__ bB,
    u16* __restrict__ hs, float* __restrict__ out_tail, int* flags)
{
  extern __shared__ __align__(16) u16 Bs[];   // [NSL][2][64][8]

  // one-time: clear any stale (poison) lines from this XCD's L1/L2
  __builtin_amdgcn_fence(__ATOMIC_ACQUIRE, "agent");

  const int bid = blockIdx.x;
  const int dir = bid >> 7;
  const int nb  = bid & 127;
  const int n0  = nb * 32;
  const u16* __restrict__ Wc   = dir ? WcB : WcF;
  const float* __restrict__ bias = dir ? bB : bF;
  int* __restrict__ fl = flags + dir * DBLK;

  const int tid  = threadIdx.x;
  const int w    = tid >> 6, lane = tid & 63;
  const int r    = lane & 15, q = lane >> 4;
  const int rq   = r >> 2;

  // stage ALL B fragments into LDS: chunk c -> [ks][nt][lane] 16B
  for (int c = tid; c < NSL * 128; c += 256) {
    int ks  = c >> 7;
    int rem = c & 127;
    int nt  = rem >> 6, l2 = rem & 63;
    int rr  = l2 & 15,  qq = l2 >> 4;
    *(short8*)&Bs[(size_t)c * 8] =
        *(const short8*)(Wc + (size_t)(n0 + nt*16 + rr) * KC + ks*32 + qq*8);
  }

  const int jbase = nb * 8;
  // lane's h-cols: j = jbase + 2*rq + nt (writer lanes r&3==0)
  float bia[2][4];
  #pragma unroll
  for (int nt = 0; nt < 2; ++nt)
    #pragma unroll
    for (int g = 0; g < 4; ++g)
      bia[nt][g] = bias[g * HID + jbase + 2*rq + nt];

  float creg[2][4];
  #pragma unroll
  for (int nt = 0; nt < 2; ++nt)
    #pragma unroll
    for (int rg = 0; rg < 4; ++rg) creg[nt][rg] = 0.f;

  const int row_a = w * 16 + r;

  // prefetch x-part A fragments for the first step
  short8 ax[8];
  {
    const int tt0 = dir ? (T_SEQ - 1) : 0;
    const u16* axr = xb + ((size_t)tt0 * BATCH + row_a) * INP;
    #pragma unroll
    for (int kx = 0; kx < 8; ++kx) ax[kx] = *(const short8*)(axr + kx*32 + q*8);
  }
  __syncthreads();   // Bs staging complete

  for (int s = 0; s < T_SEQ; ++s) {
    const int tt = dir ? (T_SEQ - 1 - s) : s;

    f32x4 acc[2];
    acc[0] = (f32x4)(0.f); acc[1] = (f32x4)(0.f);

    // h part: A = h_prev row read from hs (normal cached loads, flag-gated)
    if (s > 0) {
      const int tp = dir ? (T_SEQ - s) : (s - 1);
      const u16* __restrict__ arow =
          hs + ((size_t)tp * BATCH + row_a) * 2048 + dir * HID;
      #pragma unroll
      for (int ks = 0; ks < 32; ++ks) {
        short8 a  = *(const short8*)(arow + ks*32 + q*8);
        short8 b0 = *(const short8*)&Bs[((ks*2 + 0)*64 + lane)*8];
        short8 b1 = *(const short8*)&Bs[((ks*2 + 1)*64 + lane)*8];
        acc[0] = __builtin_amdgcn_mfma_f32_16x16x32_bf16(a, b0, acc[0], 0, 0, 0);
        acc[1] = __builtin_amdgcn_mfma_f32_16x16x32_bf16(a, b1, acc[1], 0, 0, 0);
      }
    }
    // x part: prefetched registers
    #pragma unroll
    for (int kx = 0; kx < 8; ++kx) {
      int ks = 32 + kx;
      short8 b0 = *(const short8*)&Bs[((ks*2 + 0)*64 + lane)*8];
      short8 b1 = *(const short8*)&Bs[((ks*2 + 1)*64 + lane)*8];
      acc[0] = __builtin_amdgcn_mfma_f32_16x16x32_bf16(ax[kx], b0, acc[0], 0, 0, 0);
      acc[1] = __builtin_amdgcn_mfma_f32_16x16x32_bf16(ax[kx], b1, acc[1], 0, 0, 0);
    }

    // prefetch next step's x fragments (overlaps cell update)
    if (s < T_SEQ - 1) {
      const int tn = dir ? (T_SEQ - 2 - s) : (s + 1);
      const u16* axr = xb + ((size_t)tn * BATCH + row_a) * INP;
      #pragma unroll
      for (int kx = 0; kx < 8; ++kx) ax[kx] = *(const short8*)(axr + kx*32 + q*8);
    }

    // gate combine + cell update.
    // acc[nt][rg]: row = w*16+q*4+rg, gate = r&3, h-col j = jbase+2*rq+nt
    u16  hbv[2][4];
    float hnv[2][4];
    #pragma unroll
    for (int nt = 0; nt < 2; ++nt) {
      #pragma unroll
      for (int rg = 0; rg < 4; ++rg) {
        float v  = acc[nt][rg];
        float x1 = __shfl_xor(v, 1);
        float x2 = __shfl_xor(v, 2);
        float x3 = __shfl_xor(x1, 2);
        if ((r & 3) == 0) {
          float gi = v  + bia[nt][0];
          float gf = x1 + bia[nt][1];
          float go = x2 + bia[nt][2];
          float gc = x3 + bia[nt][3];
          float cn = sigm(gf) * creg[nt][rg] + sigm(gi) * tanhf_(gc);
          float hn = sigm(go) * tanhf_(cn);
          creg[nt][rg] = cn;
          hnv[nt][rg] = hn;
          hbv[nt][rg] = f2bf(hn);
        }
      }
    }
    // packed u32 write-through h stores (2 adjacent cols per writer lane)
    #pragma unroll
    for (int rg = 0; rg < 4; ++rg) {
      if ((r & 3) == 0) {
        int row = w * 16 + q * 4 + rg;
        u32 packed = (u32)hbv[0][rg] | ((u32)hbv[1][rg] << 16);
        st_u32_wt((u32*)(hs + ((size_t)tt * BATCH + row) * 2048 + dir * HID + jbase + 2*rq),
                  packed);
      }
    }

    if (s < T_SEQ - 1) {
      asm volatile("s_waitcnt vmcnt(0)" ::: "memory");  // drain h stores to IC
      __syncthreads();
      if (tid == 0) st_u32_wt((u32*)(fl + nb), (u32)(s + 1));
      if (w == 0) {
        const int tgt = s + 1;
        while (true) {
          int f0 = __hip_atomic_load(fl + 2*lane,     __ATOMIC_RELAXED, __HIP_MEMORY_SCOPE_AGENT);
          int f1 = __hip_atomic_load(fl + 2*lane + 1, __ATOMIC_RELAXED, __HIP_MEMORY_SCOPE_AGENT);
          if (__all((f0 >= tgt) && (f1 >= tgt))) break;
          __builtin_amdgcn_s_sleep(1);
        }
      }
      __syncthreads();   // no fence: hs addresses are write-once, loads flag-gated
    } else {
      // final-state outputs
      #pragma unroll
      for (int nt = 0; nt < 2; ++nt)
        #pragma unroll
        for (int rg = 0; rg < 4; ++rg)
          if ((r & 3) == 0) {
            int row = w * 16 + q * 4 + rg;
            int j   = jbase + 2*rq + nt;
            st_f32_wt(out_tail + dir * (BATCH * HID) + (size_t)row * HID + j, hnv[nt][rg]);
            st_f32_wt(out_tail + 2 * (BATCH * HID) + dir * (BATCH * HID) + (size_t)row * HID + j, creg[nt][rg]);
          }
    }
  }
}

// ---------------------------------------------------------------------------
// Final FC: out[16384][1024] = hs[16384][2048] @ WfcT^T + b_fc, f32 out.
// ---------------------------------------------------------------------------
__global__ __launch_bounds__(256) void fc_kernel(
    const u16* __restrict__ hs, const u16* __restrict__ WfcT,
    const float* __restrict__ bfc, float* __restrict__ out)
{
  const int m0 = blockIdx.x * 128, n0 = blockIdx.y * 128;
  __shared__ __align__(16) u16 As[128 * 32];
  __shared__ __align__(16) u16 Bs[128 * 32];
  const int tid = threadIdx.x;
  const int w = tid >> 6, lane = tid & 63;
  const int r = lane & 15, q = lane >> 4;
  const int wy = w >> 1, wx = w & 1;

  f32x4 acc[4][4];
  #pragma unroll
  for (int a = 0; a < 4; ++a)
    #pragma unroll
    for (int b = 0; b < 4; ++b) acc[a][b] = (f32x4)(0.f);

  const int lr = tid >> 1, lk = (tid & 1) * 16;

  for (int k0 = 0; k0 < 2048; k0 += 32) {
    __syncthreads();
    *(short8*)&As[lr * 32 + lk]     = *(const short8*)(hs   + (size_t)(m0 + lr) * 2048 + k0 + lk);
    *(short8*)&As[lr * 32 + lk + 8] = *(const short8*)(hs   + (size_t)(m0 + lr) * 2048 + k0 + lk + 8);
    *(short8*)&Bs[lr * 32 + lk]     = *(const short8*)(WfcT + (size_t)(n0 + lr) * 2048 + k0 + lk);
    *(short8*)&Bs[lr * 32 + lk + 8] = *(const short8*)(WfcT + (size_t)(n0 + lr) * 2048 + k0 + lk + 8);
    __syncthreads();

    short8 af[4], bf[4];
    #pragma unroll
    for (int mt = 0; mt < 4; ++mt)
      af[mt] = *(const short8*)&As[(wy * 64 + mt * 16 + r) * 32 + q * 8];
    #pragma unroll
    for (int nt = 0; nt < 4; ++nt)
      bf[nt] = *(const short8*)&Bs[(wx * 64 + nt * 16 + r) * 32 + q * 8];
    #pragma unroll
    for (int mt = 0; mt < 4; ++mt)
      #pragma unroll
      for (int nt = 0; nt < 4; ++nt)
        acc[mt][nt] = __builtin_amdgcn_mfma_f32_16x16x32_bf16(af[mt], bf[nt], acc[mt][nt], 0, 0, 0);
  }

  #pragma unroll
  for (int mt = 0; mt < 4; ++mt)
    #pragma unroll
    for (int nt = 0; nt < 4; ++nt)
      #pragma unroll
      for (int reg = 0; reg < 4; ++reg) {
        int m = m0 + wy * 64 + mt * 16 + q * 4 + reg;
        int n = n0 + wx * 64 + nt * 16 + r;
        out[(size_t)m * OUTD + n] = acc[mt][nt][reg] + bfc[n];
      }
}

// ---------------------------------------------------------------------------
extern "C" void kernel_launch(void* const* d_in, const int* in_sizes, int n_in,
                              void* d_out, int out_size, void* d_ws, size_t ws_size,
                              hipStream_t stream)
{
  const float* x   = (const float*)d_in[0];
  const float* WxF = (const float*)d_in[1];
  const float* WhF = (const float*)d_in[2];
  const float* bF  = (const float*)d_in[3];
  const float* WxB = (const float*)d_in[4];
  const float* WhB = (const float*)d_in[5];
  const float* bB  = (const float*)d_in[6];
  const float* Wfc = (const float*)d_in[7];
  const float* bfc = (const float*)d_in[8];
  float* out = (float*)d_out;

  char* ws = (char*)d_ws;
  u16*  WcF   = (u16*)(ws + 0);          // 10485760
  u16*  WcB   = (u16*)(ws + 10485760);   // 10485760
  u16*  WfcT  = (u16*)(ws + 20971520);   // 4194304
  u16*  xb    = (u16*)(ws + 25165824);   // 8388608
  u16*  hs    = (u16*)(ws + 34603008);   // 67108864
  int*  flags = (int*)(ws + 101711872);  // 1KB (256 ints)

  hipMemsetAsync(flags, 0, 1024, stream);   // barrier flags

  hipFuncSetAttribute((const void*)lstm_persist,
                      hipFuncAttributeMaxDynamicSharedMemorySize, LDSB);

  build_wc <<<dim3(KC/64, HID/64, 8), 256, 0, stream>>>(WhF, WxF, WhB, WxB, WcF, WcB);
  build_wfc<<<dim3(2048/64, OUTD/64), 256, 0, stream>>>(Wfc, WfcT);
  conv_x   <<<(T_SEQ*BATCH*INP)/4/256, 256, 0, stream>>>(x, xb, T_SEQ*BATCH*INP);

  lstm_persist<<<NBLK, 256, LDSB, stream>>>(WcF, WcB, xb, bF, bB,
                                            hs, out + 16777216, flags);

  fc_kernel<<<dim3(16384/128, OUTD/128), 256, 0, stream>>>(hs, WfcT, bfc, out);
}